// Round 1
// baseline (380.629 us; speedup 1.0000x reference)
//
#include <hip/hip_runtime.h>
#include <stdint.h>

typedef unsigned short u16;
typedef __attribute__((ext_vector_type(8))) short bf16x8;
typedef __attribute__((ext_vector_type(4))) float f32x4;

#define EMB 1024
#define SLEN 2048
#define NB 4
#define NHD 16
#define DKH 64

__device__ __forceinline__ u16 f2bf(float f) {
  uint32_t u = __float_as_uint(f);
  u = (u + 0x7fffu + ((u >> 16) & 1u)) >> 16;
  return (u16)u;
}

__device__ __forceinline__ void load_lds16(const void* g, void* l) {
  __builtin_amdgcn_global_load_lds(
      (const __attribute__((address_space(1))) uint32_t*)g,
      (__attribute__((address_space(3))) uint32_t*)l, 16, 0, 0);
}

__global__ __launch_bounds__(256) void cvt_f32_bf16(const float* __restrict__ in,
                                                    u16* __restrict__ out, int n4) {
  int i = blockIdx.x * 256 + threadIdx.x;
  if (i >= n4) return;
  float4 v = ((const float4*)in)[i];
  union { u16 h[4]; uint64_t q; } o;
  o.h[0] = f2bf(v.x); o.h[1] = f2bf(v.y); o.h[2] = f2bf(v.z); o.h[3] = f2bf(v.w);
  ((uint64_t*)out)[i] = o.q;
}

// C = A[M,K] * W[N,K]^T ; 128x128 tile, BK=32, 4 waves, m97 structure.
template<int OUTF32>
__device__ __forceinline__ void gemm_body(const u16* __restrict__ A,
                                          const u16* __restrict__ W,
                                          void* __restrict__ C) {
  __shared__ __align__(16) u16 At[128 * 32];
  __shared__ __align__(16) u16 Bt[128 * 32];
  const int tid = threadIdx.x;
  const int l = tid & 63, w = tid >> 6;
  const int wm = w >> 1, wn = w & 1;
  const int bm = blockIdx.y * 128, bn = blockIdx.x * 128;
  const int lr = l & 15, lg = l >> 4;

  f32x4 acc[4][4] = {};

  const int e0 = w * 1024 + l * 8;
  const int r0 = e0 >> 5, c0 = e0 & 31;
  const int e1 = e0 + 512;
  const int r1 = e1 >> 5, c1 = e1 & 31;
  const u16* Ag0 = A + (size_t)(bm + r0) * EMB + c0;
  const u16* Ag1 = A + (size_t)(bm + r1) * EMB + c1;
  const u16* Wg0 = W + (size_t)(bn + r0) * EMB + c0;
  const u16* Wg1 = W + (size_t)(bn + r1) * EMB + c1;
  u16* Al = At + w * 1024;
  u16* Bl = Bt + w * 1024;

  for (int k0 = 0; k0 < EMB; k0 += 32) {
    load_lds16(Ag0 + k0, Al);
    load_lds16(Ag1 + k0, Al + 512);
    load_lds16(Wg0 + k0, Bl);
    load_lds16(Wg1 + k0, Bl + 512);
    asm volatile("s_waitcnt vmcnt(0)" ::: "memory");
    __syncthreads();
    bf16x8 af[4], bf[4];
#pragma unroll
    for (int i = 0; i < 4; ++i)
      af[i] = *(const bf16x8*)(At + (wm * 64 + i * 16 + lr) * 32 + lg * 8);
#pragma unroll
    for (int j = 0; j < 4; ++j)
      bf[j] = *(const bf16x8*)(Bt + (wn * 64 + j * 16 + lr) * 32 + lg * 8);
#pragma unroll
    for (int i = 0; i < 4; ++i)
#pragma unroll
      for (int j = 0; j < 4; ++j)
        acc[i][j] = __builtin_amdgcn_mfma_f32_16x16x32_bf16(af[i], bf[j], acc[i][j], 0, 0, 0);
    __syncthreads();
  }
#pragma unroll
  for (int i = 0; i < 4; ++i) {
    const int mb = bm + wm * 64 + i * 16 + lg * 4;
#pragma unroll
    for (int j = 0; j < 4; ++j) {
      const int col = bn + wn * 64 + j * 16 + lr;
#pragma unroll
      for (int r = 0; r < 4; ++r) {
        if (OUTF32)
          ((float*)C)[(size_t)(mb + r) * EMB + col] = acc[i][j][r];
        else
          ((u16*)C)[(size_t)(mb + r) * EMB + col] = f2bf(acc[i][j][r]);
      }
    }
  }
}

__global__ __launch_bounds__(256) void gemm_qkv(
    const u16* __restrict__ A,
    const u16* __restrict__ w0, const u16* __restrict__ w1, const u16* __restrict__ w2,
    u16* __restrict__ o0, u16* __restrict__ o1, u16* __restrict__ o2) {
  const u16* W = (blockIdx.z == 0) ? w0 : ((blockIdx.z == 1) ? w1 : w2);
  u16* O = (blockIdx.z == 0) ? o0 : ((blockIdx.z == 1) ? o1 : o2);
  gemm_body<0>(A, W, O);
}

__global__ __launch_bounds__(256) void gemm_out(const u16* __restrict__ A,
                                                const u16* __restrict__ W,
                                                float* __restrict__ C) {
  gemm_body<1>(A, W, C);
}

// Flash attention. Q,K,V,O in [B,S,E] bf16 layout, head h at cols [h*64, h*64+64).
// Block: 4 waves; wave w owns q-rows [q0+16w, q0+16w+16). KV tiles of 64.
__global__ __launch_bounds__(256) void attn_fwd(const u16* __restrict__ Q,
                                                const u16* __restrict__ K,
                                                const u16* __restrict__ V,
                                                u16* __restrict__ O) {
  __shared__ __align__(16) u16 Kt[64 * 64];     // [key][d], rows 128B, XOR-swizzled
  __shared__ __align__(16) u16 Vt[64 * 72];     // [d][key] transposed, rows 144B, swizzled
  __shared__ __align__(16) u16 Pl[4 * 16 * 64]; // per-wave P, rows 128B, swizzled

  const int tid = threadIdx.x;
  const int l = tid & 63, w = tid >> 6;
  const int lr = l & 15, lg = l >> 4;
  const int bh = blockIdx.y;
  const int b = bh >> 4, h = bh & 15;
  const int q0 = blockIdx.x * 64;
  const int qw = q0 + w * 16;
  const size_t base = ((size_t)b * SLEN) * EMB + h * DKH;

  bf16x8 qf[2];
#pragma unroll
  for (int dk = 0; dk < 2; ++dk)
    qf[dk] = *(const bf16x8*)(Q + base + (size_t)(qw + lr) * EMB + dk * 32 + lg * 8);

  f32x4 acc_o[4] = {};
  float mrow[4], lsum[4];
#pragma unroll
  for (int r = 0; r < 4; ++r) { mrow[r] = -1e30f; lsum[r] = 0.f; }

  for (int t = 0; t < 32; ++t) {
    const int kv0 = t * 64;
    // stage K: linear LDS dest, pre-swizzled global source (rule #21)
#pragma unroll
    for (int p = 0; p < 2; ++p) {
      const int Lb = w * 2048 + p * 1024 + l * 16;
      const int row = Lb >> 7;
      const int cb = (Lb & 127) ^ ((row & 7) << 4);
      load_lds16(K + base + (size_t)(kv0 + row) * EMB + (cb >> 1),
                 (char*)Kt + w * 2048 + p * 1024);
    }
    // stage V transposed: lane-spread chunks so ds_write banks are spread by key
#pragma unroll
    for (int p = 0; p < 2; ++p) {
      const int chunk = p * 256 + tid;
      const int kk = chunk & 63;
      const int d0 = (chunk >> 6) * 8;
      bf16x8 vv = *(const bf16x8*)(V + base + (size_t)(kv0 + kk) * EMB + d0);
#pragma unroll
      for (int j = 0; j < 8; ++j) {
        const int d = d0 + j;
        *(u16*)((char*)Vt + d * 144 + ((kk * 2) ^ ((d & 7) << 4))) = (u16)vv[j];
      }
    }
    asm volatile("s_waitcnt vmcnt(0)" ::: "memory");
    __syncthreads();

    // S = Q K^T : per wave 16(q) x 64(key)
    f32x4 sa[4] = {};
#pragma unroll
    for (int n = 0; n < 4; ++n) {
      const int key = n * 16 + lr;
      const int swz = (key & 7) << 4;
#pragma unroll
      for (int dk = 0; dk < 2; ++dk) {
        bf16x8 kf = *(const bf16x8*)((char*)Kt + key * 128 + ((dk * 64 + lg * 16) ^ swz));
        sa[n] = __builtin_amdgcn_mfma_f32_16x16x32_bf16(qf[dk], kf, sa[n], 0, 0, 0);
      }
    }

    float pmax[4];
#pragma unroll
    for (int r = 0; r < 4; ++r) {
      sa[0][r] *= 0.125f; sa[1][r] *= 0.125f; sa[2][r] *= 0.125f; sa[3][r] *= 0.125f;
      pmax[r] = fmaxf(fmaxf(sa[0][r], sa[1][r]), fmaxf(sa[2][r], sa[3][r]));
    }
#pragma unroll
    for (int m = 1; m <= 8; m <<= 1)
#pragma unroll
      for (int r = 0; r < 4; ++r)
        pmax[r] = fmaxf(pmax[r], __shfl_xor(pmax[r], m, 64));

    float scale[4], psum[4];
#pragma unroll
    for (int r = 0; r < 4; ++r) {
      const float mn = fmaxf(mrow[r], pmax[r]);
      scale[r] = __expf(mrow[r] - mn);
      mrow[r] = mn;
      psum[r] = 0.f;
    }
#pragma unroll
    for (int n = 0; n < 4; ++n)
#pragma unroll
      for (int r = 0; r < 4; ++r) {
        const float p = __expf(sa[n][r] - mrow[r]);
        sa[n][r] = p;
        psum[r] += p;
      }
#pragma unroll
    for (int m = 1; m <= 8; m <<= 1)
#pragma unroll
      for (int r = 0; r < 4; ++r)
        psum[r] += __shfl_xor(psum[r], m, 64);
#pragma unroll
    for (int r = 0; r < 4; ++r)
      lsum[r] = lsum[r] * scale[r] + psum[r];
#pragma unroll
    for (int nd = 0; nd < 4; ++nd)
#pragma unroll
      for (int r = 0; r < 4; ++r)
        acc_o[nd][r] *= scale[r];

    // P (acc layout) -> per-wave LDS (bf16, swizzled) -> A-fragment layout
#pragma unroll
    for (int n = 0; n < 4; ++n)
#pragma unroll
      for (int r = 0; r < 4; ++r) {
        const int row = lg * 4 + r;
        *(u16*)((char*)Pl + w * 2048 + row * 128 +
                (((n * 16 + lr) * 2) ^ ((row & 7) << 4))) = f2bf(sa[n][r]);
      }

    // O += P V
#pragma unroll
    for (int kk = 0; kk < 2; ++kk) {
      bf16x8 pf = *(const bf16x8*)((char*)Pl + w * 2048 + lr * 128 +
                                   ((kk * 64 + lg * 16) ^ ((lr & 7) << 4)));
#pragma unroll
      for (int nd = 0; nd < 4; ++nd) {
        const int vr = nd * 16 + lr;
        bf16x8 vf = *(const bf16x8*)((char*)Vt + vr * 144 +
                                     ((kk * 64 + lg * 16) ^ ((vr & 7) << 4)));
        acc_o[nd] = __builtin_amdgcn_mfma_f32_16x16x32_bf16(pf, vf, acc_o[nd], 0, 0, 0);
      }
    }
    __syncthreads();
  }

#pragma unroll
  for (int nd = 0; nd < 4; ++nd)
#pragma unroll
    for (int r = 0; r < 4; ++r) {
      const int s = qw + lg * 4 + r;
      O[base + (size_t)s * EMB + nd * 16 + lr] = f2bf(acc_o[nd][r] / lsum[r]);
    }
}

extern "C" void kernel_launch(void* const* d_in, const int* in_sizes, int n_in,
                              void* d_out, int out_size, void* d_ws, size_t ws_size,
                              hipStream_t stream) {
  const float* x  = (const float*)d_in[0];
  const float* wq = (const float*)d_in[1];
  const float* wk = (const float*)d_in[2];
  const float* wv = (const float*)d_in[3];
  const float* wo = (const float*)d_in[4];

  char* ws = (char*)d_ws;
  u16* xb  = (u16*)(ws + 0);          // 16,777,216 B
  u16* wqb = (u16*)(ws + 16777216);   //  2,097,152 B
  u16* wkb = (u16*)(ws + 18874368);
  u16* wvb = (u16*)(ws + 20971520);
  u16* wob = (u16*)(ws + 23068672);
  u16* Qb  = (u16*)(ws + 25165824);   // 16,777,216 B each
  u16* Kb  = (u16*)(ws + 41943040);
  u16* Vb  = (u16*)(ws + 58720256);
  u16* AO  = (u16*)(ws + 75497472);   // end: 92,274,688 B

  cvt_f32_bf16<<<2097152 / 256, 256, 0, stream>>>(x, xb, 2097152);
  cvt_f32_bf16<<<262144 / 256, 256, 0, stream>>>(wq, wqb, 262144);
  cvt_f32_bf16<<<262144 / 256, 256, 0, stream>>>(wk, wkb, 262144);
  cvt_f32_bf16<<<262144 / 256, 256, 0, stream>>>(wv, wvb, 262144);
  cvt_f32_bf16<<<262144 / 256, 256, 0, stream>>>(wo, wob, 262144);

  gemm_qkv<<<dim3(8, 64, 3), 256, 0, stream>>>(xb, wqb, wkb, wvb, Qb, Kb, Vb);
  attn_fwd<<<dim3(32, 64), 256, 0, stream>>>(Qb, Kb, Vb, AO);
  gemm_out<<<dim3(8, 64), 256, 0, stream>>>(AO, wob, (float*)d_out);
}

// Round 2
// 243.153 us; speedup vs baseline: 1.5654x; 1.5654x over previous
//
#include <hip/hip_runtime.h>
#include <stdint.h>

typedef unsigned short u16;
typedef __attribute__((ext_vector_type(8))) short bf16x8;
typedef __attribute__((ext_vector_type(4))) float f32x4;
typedef __attribute__((ext_vector_type(16))) float f32x16;

#define EMB 1024
#define SLEN 2048
#define NHD 16
#define DKH 64

__device__ __forceinline__ u16 f2bf(float f) {
  uint32_t u = __float_as_uint(f);
  u = (u + 0x7fffu + ((u >> 16) & 1u)) >> 16;
  return (u16)u;
}

__device__ __forceinline__ void load_lds16(const void* g, void* l) {
  __builtin_amdgcn_global_load_lds(
      (const __attribute__((address_space(1))) uint32_t*)g,
      (__attribute__((address_space(3))) uint32_t*)l, 16, 0, 0);
}

__global__ __launch_bounds__(256) void cvt_f32_bf16(const float* __restrict__ in,
                                                    u16* __restrict__ out, int n4) {
  int i = blockIdx.x * 256 + threadIdx.x;
  if (i >= n4) return;
  float4 v = ((const float4*)in)[i];
  union { u16 h[4]; uint64_t q; } o;
  o.h[0] = f2bf(v.x); o.h[1] = f2bf(v.y); o.h[2] = f2bf(v.z); o.h[3] = f2bf(v.w);
  ((uint64_t*)out)[i] = o.q;
}

// C = A[M,K] * W[N,K]^T ; 128x128 tile, BK=32, 4 waves, m97 structure.
// MODE 0: bf16 out [M,N] (K-proj). MODE 1: bf16 out scaled 0.125 (Q-proj).
// MODE 2: bf16 out transposed per-head [B,H,D,S] (V-proj). MODE 3: f32 out.
template<int MODE>
__device__ __forceinline__ void gemm_body(const u16* __restrict__ A,
                                          const u16* __restrict__ W,
                                          void* __restrict__ C) {
  __shared__ __align__(16) u16 At[128 * 32];
  __shared__ __align__(16) u16 Bt[128 * 32];
  const int tid = threadIdx.x;
  const int l = tid & 63, w = tid >> 6;
  const int wm = w >> 1, wn = w & 1;
  const int bm = blockIdx.y * 128, bn = blockIdx.x * 128;
  const int lr = l & 15, lg = l >> 4;

  f32x4 acc[4][4] = {};

  const int e0 = w * 1024 + l * 8;
  const int r0 = e0 >> 5, c0 = e0 & 31;
  const int e1 = e0 + 512;
  const int r1 = e1 >> 5, c1 = e1 & 31;
  const u16* Ag0 = A + (size_t)(bm + r0) * EMB + c0;
  const u16* Ag1 = A + (size_t)(bm + r1) * EMB + c1;
  const u16* Wg0 = W + (size_t)(bn + r0) * EMB + c0;
  const u16* Wg1 = W + (size_t)(bn + r1) * EMB + c1;
  u16* Al = At + w * 1024;
  u16* Bl = Bt + w * 1024;

  for (int k0 = 0; k0 < EMB; k0 += 32) {
    load_lds16(Ag0 + k0, Al);
    load_lds16(Ag1 + k0, Al + 512);
    load_lds16(Wg0 + k0, Bl);
    load_lds16(Wg1 + k0, Bl + 512);
    asm volatile("s_waitcnt vmcnt(0)" ::: "memory");
    __syncthreads();
    bf16x8 af[4], bf[4];
#pragma unroll
    for (int i = 0; i < 4; ++i)
      af[i] = *(const bf16x8*)(At + (wm * 64 + i * 16 + lr) * 32 + lg * 8);
#pragma unroll
    for (int j = 0; j < 4; ++j)
      bf[j] = *(const bf16x8*)(Bt + (wn * 64 + j * 16 + lr) * 32 + lg * 8);
#pragma unroll
    for (int i = 0; i < 4; ++i)
#pragma unroll
      for (int j = 0; j < 4; ++j)
        acc[i][j] = __builtin_amdgcn_mfma_f32_16x16x32_bf16(af[i], bf[j], acc[i][j], 0, 0, 0);
    __syncthreads();
  }

  if (MODE == 2) {
    // V^T: out[((b*16 + h)*64 + d)*2048 + s], 4 consecutive s per (i,j) -> u64 store
#pragma unroll
    for (int i = 0; i < 4; ++i) {
      const int m0 = bm + wm * 64 + i * 16 + lg * 4;
      const int bb = m0 >> 11;
      const int ss = m0 & 2047;
#pragma unroll
      for (int j = 0; j < 4; ++j) {
        const int n = bn + wn * 64 + j * 16 + lr;
        const int hh = n >> 6, dd = n & 63;
        union { u16 h[4]; uint64_t q; } pk;
#pragma unroll
        for (int r = 0; r < 4; ++r) pk.h[r] = f2bf(acc[i][j][r]);
        *(uint64_t*)((u16*)C + ((size_t)((bb * 16 + hh) * 64 + dd)) * 2048 + ss) = pk.q;
      }
    }
  } else {
#pragma unroll
    for (int i = 0; i < 4; ++i) {
      const int mb = bm + wm * 64 + i * 16 + lg * 4;
#pragma unroll
      for (int j = 0; j < 4; ++j) {
        const int col = bn + wn * 64 + j * 16 + lr;
#pragma unroll
        for (int r = 0; r < 4; ++r) {
          float v = acc[i][j][r];
          if (MODE == 1) v *= 0.125f;
          if (MODE == 3)
            ((float*)C)[(size_t)(mb + r) * EMB + col] = v;
          else
            ((u16*)C)[(size_t)(mb + r) * EMB + col] = f2bf(v);
        }
      }
    }
  }
}

__global__ __launch_bounds__(256) void gemm_qkv(
    const u16* __restrict__ A,
    const u16* __restrict__ wq, const u16* __restrict__ wk, const u16* __restrict__ wv,
    u16* __restrict__ Qo, u16* __restrict__ Ko, u16* __restrict__ Vo) {
  if (blockIdx.z == 0) gemm_body<1>(A, wq, Qo);
  else if (blockIdx.z == 1) gemm_body<0>(A, wk, Ko);
  else gemm_body<2>(A, wv, Vo);
}

__global__ __launch_bounds__(256) void gemm_out(const u16* __restrict__ A,
                                                const u16* __restrict__ W,
                                                float* __restrict__ C) {
  gemm_body<3>(A, W, C);
}

// Flash attention, m214-style: 4 waves x 32 q-rows, KV tiles of 64, swapped
// QK^T (mfma(K,Q)) with 32x32x16 MFMA, register softmax, double-buffered K/V^T
// staged via global_load_lds with pre-swizzled source (XOR (row&7)<<4).
// Q is pre-scaled by 0.125; V^T is [B,H,D,S].
__global__ __launch_bounds__(256) void attn_fwd(const u16* __restrict__ Q,
                                                const u16* __restrict__ K,
                                                const u16* __restrict__ VT,
                                                u16* __restrict__ O) {
  __shared__ __align__(16) u16 Kt[2][64 * 64];
  __shared__ __align__(16) u16 Vt[2][64 * 64];
  const int tid = threadIdx.x;
  const int l = tid & 63, w = tid >> 6;
  const int ql = l & 31, hi = l >> 5;
  const int bh = blockIdx.y, b = bh >> 4, h = bh & 15;
  const int qw = blockIdx.x * 128 + w * 32;
  const size_t qkb = ((size_t)b * SLEN) * EMB + h * DKH;
  const size_t vb = (size_t)bh * DKH * SLEN;

  // Q fragments (B-operand): lane holds Q[qw+ql][ks*16 + hi*8 + j]
  bf16x8 qf[4];
#pragma unroll
  for (int ks = 0; ks < 4; ++ks)
    qf[ks] = *(const bf16x8*)(Q + qkb + (size_t)(qw + ql) * EMB + ks * 16 + hi * 8);

  f32x16 accd[2] = {};
  float mrow = -1e30f, lsum = 0.f;

  auto stage = [&](int buf, int t) {
#pragma unroll
    for (int p = 0; p < 2; ++p) {
      const int Lb = w * 2048 + p * 1024 + l * 16;
      const int row = Lb >> 7;                       // 0..63
      const int cb = (Lb & 127) ^ ((row & 7) << 4);  // pre-swizzled source col
      load_lds16(K + qkb + (size_t)(t * 64 + row) * EMB + (cb >> 1),
                 (char*)(Kt[buf]) + w * 2048 + p * 1024);
      load_lds16(VT + vb + (size_t)row * SLEN + t * 64 + (cb >> 1),
                 (char*)(Vt[buf]) + w * 2048 + p * 1024);
    }
  };

  stage(0, 0);
#pragma unroll 1
  for (int t = 0; t < 32; ++t) {
    const int cur = t & 1;
    if (t < 31) {
      stage(cur ^ 1, t + 1);
      asm volatile("s_waitcnt vmcnt(4)" ::: "memory");  // keep next tile in flight
    } else {
      asm volatile("s_waitcnt vmcnt(0)" ::: "memory");
    }
    __builtin_amdgcn_s_barrier();

    // S^T = K @ Q : D[key][q], sacc[kf2] covers keys kf2*32..+31
    f32x16 sacc[2] = {};
#pragma unroll
    for (int kf2 = 0; kf2 < 2; ++kf2) {
      const int row = kf2 * 32 + ql;
      const int swz = (row & 7) << 4;
#pragma unroll
      for (int ks = 0; ks < 4; ++ks) {
        bf16x8 kf = *(const bf16x8*)((char*)(Kt[cur]) + row * 128 +
                                     ((ks * 32 + hi * 16) ^ swz));
        sacc[kf2] = __builtin_amdgcn_mfma_f32_32x32x16_bf16(kf, qf[ks], sacc[kf2], 0, 0, 0);
      }
    }

    // online softmax: lane owns column q=ql; keys split with partner lane (xor 32)
    float pmax = fmaxf(sacc[0][0], sacc[1][0]);
#pragma unroll
    for (int r = 1; r < 16; ++r)
      pmax = fmaxf(pmax, fmaxf(sacc[0][r], sacc[1][r]));
    pmax = fmaxf(pmax, __shfl_xor(pmax, 32, 64));

    if (__any(pmax > mrow + 8.f)) {  // T13 defer-max
      const float mnew = fmaxf(mrow, pmax);
      const float sc = __expf(mrow - mnew);
      mrow = mnew;
      lsum *= sc;
#pragma unroll
      for (int reg = 0; reg < 16; ++reg) {
        const float scT = __shfl(sc, (reg & 3) + 8 * (reg >> 2) + 4 * hi, 64);
        accd[0][reg] *= scT;
        accd[1][reg] *= scT;
      }
    }

    float psum = 0.f;
#pragma unroll
    for (int kf2 = 0; kf2 < 2; ++kf2)
#pragma unroll
      for (int r = 0; r < 16; ++r) {
        const float p = __expf(sacc[kf2][r] - mrow);
        sacc[kf2][r] = p;
        psum += p;
      }
    psum += __shfl_xor(psum, 32, 64);
    lsum += psum;

    // pack P to bf16 dwords: Dd[kf2][rr][dwi] = keys kf2*32 + 8rr + 4hi + 2dwi + {0,1}
    uint32_t Dd[2][4][2];
#pragma unroll
    for (int kf2 = 0; kf2 < 2; ++kf2)
#pragma unroll
      for (int rr = 0; rr < 4; ++rr)
#pragma unroll
        for (int dwi = 0; dwi < 2; ++dwi) {
          uint32_t d;
          float lo = sacc[kf2][rr * 4 + 2 * dwi];
          float hv = sacc[kf2][rr * 4 + 2 * dwi + 1];
          asm("v_cvt_pk_bf16_f32 %0, %1, %2" : "=v"(d) : "v"(lo), "v"(hv));
          Dd[kf2][rr][dwi] = d;
        }

    // redistribute to PV A-fragments: pa[ks].dw[m] = keys ks*16 + hi*8 + 2m + {0,1}
#pragma unroll
    for (int ks = 0; ks < 4; ++ks) {
      const int kf2 = ks >> 1, rA = 2 * (ks & 1);
      const uint32_t keep0 = hi ? Dd[kf2][rA + 1][0] : Dd[kf2][rA][0];
      const uint32_t send0 = hi ? Dd[kf2][rA][0] : Dd[kf2][rA + 1][0];
      const uint32_t keep1 = hi ? Dd[kf2][rA + 1][1] : Dd[kf2][rA][1];
      const uint32_t send1 = hi ? Dd[kf2][rA][1] : Dd[kf2][rA + 1][1];
      const uint32_t r0 = (uint32_t)__shfl_xor((int)send0, 32, 64);
      const uint32_t r1 = (uint32_t)__shfl_xor((int)send1, 32, 64);
      union { uint32_t d[4]; bf16x8 v; } pa;
      pa.d[0] = hi ? r0 : keep0;
      pa.d[1] = hi ? r1 : keep1;
      pa.d[2] = hi ? keep0 : r0;
      pa.d[3] = hi ? keep1 : r1;
#pragma unroll
      for (int df = 0; df < 2; ++df) {
        const int vr = df * 32 + ql;
        bf16x8 vf = *(const bf16x8*)((char*)(Vt[cur]) + vr * 128 +
                                     ((ks * 32 + hi * 16) ^ ((vr & 7) << 4)));
        accd[df] = __builtin_amdgcn_mfma_f32_32x32x16_bf16(pa.v, vf, accd[df], 0, 0, 0);
      }
    }
    __builtin_amdgcn_s_barrier();
  }

#pragma unroll
  for (int reg = 0; reg < 16; ++reg) {
    const int rowq = (reg & 3) + 8 * (reg >> 2) + 4 * hi;
    const float li = 1.0f / __shfl(lsum, rowq, 64);
    u16* orow = O + qkb + (size_t)(qw + rowq) * EMB;
    orow[ql] = f2bf(accd[0][reg] * li);
    orow[32 + ql] = f2bf(accd[1][reg] * li);
  }
}

extern "C" void kernel_launch(void* const* d_in, const int* in_sizes, int n_in,
                              void* d_out, int out_size, void* d_ws, size_t ws_size,
                              hipStream_t stream) {
  const float* x  = (const float*)d_in[0];
  const float* wq = (const float*)d_in[1];
  const float* wk = (const float*)d_in[2];
  const float* wv = (const float*)d_in[3];
  const float* wo = (const float*)d_in[4];

  char* ws = (char*)d_ws;
  u16* xb  = (u16*)(ws + 0);          // 16 MB
  u16* wqb = (u16*)(ws + 16777216);   //  2 MB each
  u16* wkb = (u16*)(ws + 18874368);
  u16* wvb = (u16*)(ws + 20971520);
  u16* wob = (u16*)(ws + 23068672);
  u16* Qb  = (u16*)(ws + 25165824);   // 16 MB, [B,S,E], pre-scaled 0.125
  u16* Kb  = (u16*)(ws + 41943040);   // 16 MB, [B,S,E]
  u16* VTb = (u16*)(ws + 58720256);   // 16 MB, [B,H,D,S]
  u16* AO  = (u16*)(ws + 75497472);   // 16 MB, [B,S,E]

  cvt_f32_bf16<<<2097152 / 256, 256, 0, stream>>>(x, xb, 2097152);
  cvt_f32_bf16<<<262144 / 256, 256, 0, stream>>>(wq, wqb, 262144);
  cvt_f32_bf16<<<262144 / 256, 256, 0, stream>>>(wk, wkb, 262144);
  cvt_f32_bf16<<<262144 / 256, 256, 0, stream>>>(wv, wvb, 262144);
  cvt_f32_bf16<<<262144 / 256, 256, 0, stream>>>(wo, wob, 262144);

  gemm_qkv<<<dim3(8, 64, 3), 256, 0, stream>>>(xb, wqb, wkb, wvb, Qb, Kb, VTb);
  attn_fwd<<<dim3(16, 64), 256, 0, stream>>>(Qb, Kb, VTb, AO);
  gemm_out<<<dim3(8, 64), 256, 0, stream>>>(AO, wob, (float*)d_out);
}

// Round 3
// 242.720 us; speedup vs baseline: 1.5682x; 1.0018x over previous
//
#include <hip/hip_runtime.h>
#include <stdint.h>

typedef unsigned short u16;
typedef __attribute__((ext_vector_type(8))) short bf16x8;
typedef __attribute__((ext_vector_type(4))) float f32x4;
typedef __attribute__((ext_vector_type(16))) float f32x16;

#define EMB 1024
#define SLEN 2048
#define NHD 16
#define DKH 64

__device__ __forceinline__ u16 f2bf(float f) {
  uint32_t u = __float_as_uint(f);
  u = (u + 0x7fffu + ((u >> 16) & 1u)) >> 16;
  return (u16)u;
}

__device__ __forceinline__ float max3f(float a, float b, float c) {
  float d;
  asm("v_max3_f32 %0, %1, %2, %3" : "=v"(d) : "v"(a), "v"(b), "v"(c));
  return d;
}

__device__ __forceinline__ void load_lds16(const void* g, void* l) {
  __builtin_amdgcn_global_load_lds(
      (const __attribute__((address_space(1))) uint32_t*)g,
      (__attribute__((address_space(3))) uint32_t*)l, 16, 0, 0);
}

__global__ __launch_bounds__(256) void cvt_f32_bf16(const float* __restrict__ in,
                                                    u16* __restrict__ out, int n4) {
  int i = blockIdx.x * 256 + threadIdx.x;
  if (i >= n4) return;
  float4 v = ((const float4*)in)[i];
  union { u16 h[4]; uint64_t q; } o;
  o.h[0] = f2bf(v.x); o.h[1] = f2bf(v.y); o.h[2] = f2bf(v.z); o.h[3] = f2bf(v.w);
  ((uint64_t*)out)[i] = o.q;
}

// C = A[M,K] * W[N,K]^T ; 128x128 tile, BK=32, 4 waves, m97 structure.
// MODE 0: bf16 out (K-proj). MODE 1: bf16 out scaled 0.125*log2e (Q-proj).
// MODE 2: bf16 out transposed per-head [B,H,D,S] (V-proj). MODE 3: f32 out.
template<int MODE>
__device__ __forceinline__ void gemm_body(const u16* __restrict__ A,
                                          const u16* __restrict__ W,
                                          void* __restrict__ C) {
  __shared__ __align__(16) u16 At[128 * 32];
  __shared__ __align__(16) u16 Bt[128 * 32];
  const int tid = threadIdx.x;
  const int l = tid & 63, w = tid >> 6;
  const int wm = w >> 1, wn = w & 1;
  const int bm = blockIdx.y * 128, bn = blockIdx.x * 128;
  const int lr = l & 15, lg = l >> 4;

  f32x4 acc[4][4] = {};

  const int e0 = w * 1024 + l * 8;
  const int r0 = e0 >> 5, c0 = e0 & 31;
  const int e1 = e0 + 512;
  const int r1 = e1 >> 5, c1 = e1 & 31;
  const u16* Ag0 = A + (size_t)(bm + r0) * EMB + c0;
  const u16* Ag1 = A + (size_t)(bm + r1) * EMB + c1;
  const u16* Wg0 = W + (size_t)(bn + r0) * EMB + c0;
  const u16* Wg1 = W + (size_t)(bn + r1) * EMB + c1;
  u16* Al = At + w * 1024;
  u16* Bl = Bt + w * 1024;

  for (int k0 = 0; k0 < EMB; k0 += 32) {
    load_lds16(Ag0 + k0, Al);
    load_lds16(Ag1 + k0, Al + 512);
    load_lds16(Wg0 + k0, Bl);
    load_lds16(Wg1 + k0, Bl + 512);
    asm volatile("s_waitcnt vmcnt(0)" ::: "memory");
    __syncthreads();
    bf16x8 af[4], bf[4];
#pragma unroll
    for (int i = 0; i < 4; ++i)
      af[i] = *(const bf16x8*)(At + (wm * 64 + i * 16 + lr) * 32 + lg * 8);
#pragma unroll
    for (int j = 0; j < 4; ++j)
      bf[j] = *(const bf16x8*)(Bt + (wn * 64 + j * 16 + lr) * 32 + lg * 8);
#pragma unroll
    for (int i = 0; i < 4; ++i)
#pragma unroll
      for (int j = 0; j < 4; ++j)
        acc[i][j] = __builtin_amdgcn_mfma_f32_16x16x32_bf16(af[i], bf[j], acc[i][j], 0, 0, 0);
    __syncthreads();
  }

  if (MODE == 2) {
    // V^T: out[((b*16 + h)*64 + d)*2048 + s], 4 consecutive s per (i,j) -> u64 store
#pragma unroll
    for (int i = 0; i < 4; ++i) {
      const int m0 = bm + wm * 64 + i * 16 + lg * 4;
      const int bb = m0 >> 11;
      const int ss = m0 & 2047;
#pragma unroll
      for (int j = 0; j < 4; ++j) {
        const int n = bn + wn * 64 + j * 16 + lr;
        const int hh = n >> 6, dd = n & 63;
        union { u16 h[4]; uint64_t q; } pk;
#pragma unroll
        for (int r = 0; r < 4; ++r) pk.h[r] = f2bf(acc[i][j][r]);
        *(uint64_t*)((u16*)C + ((size_t)((bb * 16 + hh) * 64 + dd)) * 2048 + ss) = pk.q;
      }
    }
  } else {
#pragma unroll
    for (int i = 0; i < 4; ++i) {
      const int mb = bm + wm * 64 + i * 16 + lg * 4;
#pragma unroll
      for (int j = 0; j < 4; ++j) {
        const int col = bn + wn * 64 + j * 16 + lr;
#pragma unroll
        for (int r = 0; r < 4; ++r) {
          float v = acc[i][j][r];
          if (MODE == 1) v *= 0.18033688011112042f;  // 0.125 * log2(e)
          if (MODE == 3)
            ((float*)C)[(size_t)(mb + r) * EMB + col] = v;
          else
            ((u16*)C)[(size_t)(mb + r) * EMB + col] = f2bf(v);
        }
      }
    }
  }
}

__global__ __launch_bounds__(256) void gemm_qkv(
    const u16* __restrict__ A,
    const u16* __restrict__ wq, const u16* __restrict__ wk, const u16* __restrict__ wv,
    u16* __restrict__ Qo, u16* __restrict__ Ko, u16* __restrict__ Vo) {
  if (blockIdx.z == 0) gemm_body<1>(A, wq, Qo);
  else if (blockIdx.z == 1) gemm_body<0>(A, wk, Ko);
  else gemm_body<2>(A, wv, Vo);
}

__global__ __launch_bounds__(256) void gemm_out(const u16* __restrict__ A,
                                                const u16* __restrict__ W,
                                                float* __restrict__ C) {
  gemm_body<3>(A, W, C);
}

// Flash attention: 4 waves x 32 q-rows, KV tiles of 64, swapped QK^T
// (mfma(K,Q)) with 32x32x16 MFMA, exp2-domain register softmax,
// permlane32_swap P-redistribute, double-buffered K/V^T via global_load_lds
// with pre-swizzled source (XOR (row&7)<<4). Q pre-scaled by 0.125*log2e.
__global__ __launch_bounds__(256, 4) void attn_fwd(const u16* __restrict__ Q,
                                                   const u16* __restrict__ K,
                                                   const u16* __restrict__ VT,
                                                   u16* __restrict__ O) {
  __shared__ __align__(16) u16 Kt[2][64 * 64];
  __shared__ __align__(16) u16 Vt[2][64 * 64];
  const int tid = threadIdx.x;
  const int l = tid & 63, w = tid >> 6;
  const int ql = l & 31, hi = l >> 5;
  const int bh = blockIdx.y, b = bh >> 4, h = bh & 15;
  const int qw = blockIdx.x * 128 + w * 32;
  const size_t qkb = ((size_t)b * SLEN) * EMB + h * DKH;
  const size_t vb = (size_t)bh * DKH * SLEN;

  // Q fragments (B-operand): lane holds Q[qw+ql][ks*16 + hi*8 + j]
  bf16x8 qf[4];
#pragma unroll
  for (int ks = 0; ks < 4; ++ks)
    qf[ks] = *(const bf16x8*)(Q + qkb + (size_t)(qw + ql) * EMB + ks * 16 + hi * 8);

  f32x16 accd[2] = {};
  float mrow = -1e30f, lsum = 0.f;

  auto stage = [&](int buf, int t) {
#pragma unroll
    for (int p = 0; p < 2; ++p) {
      const int Lb = w * 2048 + p * 1024 + l * 16;
      const int row = Lb >> 7;                       // 0..63
      const int cb = (Lb & 127) ^ ((row & 7) << 4);  // pre-swizzled source col
      load_lds16(K + qkb + (size_t)(t * 64 + row) * EMB + (cb >> 1),
                 (char*)(Kt[buf]) + w * 2048 + p * 1024);
      load_lds16(VT + vb + (size_t)row * SLEN + t * 64 + (cb >> 1),
                 (char*)(Vt[buf]) + w * 2048 + p * 1024);
    }
  };

  stage(0, 0);
#pragma unroll 1
  for (int t = 0; t < 32; ++t) {
    const int cur = t & 1;
    if (t < 31) {
      stage(cur ^ 1, t + 1);
      asm volatile("s_waitcnt vmcnt(4)" ::: "memory");  // keep next tile in flight
    } else {
      asm volatile("s_waitcnt vmcnt(0)" ::: "memory");
    }
    __builtin_amdgcn_s_barrier();

    // prefetch all V fragments (A-operand rows d): overlap LDS latency w/ softmax
    bf16x8 vfr[2][4];
#pragma unroll
    for (int df = 0; df < 2; ++df) {
      const int vr = df * 32 + ql;
      const int vswz = (vr & 7) << 4;
#pragma unroll
      for (int ks = 0; ks < 4; ++ks)
        vfr[df][ks] = *(const bf16x8*)((char*)(Vt[cur]) + vr * 128 +
                                       ((ks * 32 + hi * 16) ^ vswz));
    }

    // S^T = K @ Q : D[key][q] in exp2 domain, sacc[kf2] covers keys kf2*32..+31
    f32x16 sacc[2] = {};
#pragma unroll
    for (int kf2 = 0; kf2 < 2; ++kf2) {
      const int row = kf2 * 32 + ql;
      const int swz = (row & 7) << 4;
#pragma unroll
      for (int ks = 0; ks < 4; ++ks) {
        bf16x8 kf = *(const bf16x8*)((char*)(Kt[cur]) + row * 128 +
                                     ((ks * 32 + hi * 16) ^ swz));
        sacc[kf2] = __builtin_amdgcn_mfma_f32_32x32x16_bf16(kf, qf[ks], sacc[kf2], 0, 0, 0);
      }
    }

    // online softmax (exp2 domain): lane owns column q=ql; keys split with
    // partner lane (xor 32)
    float pm[8];
#pragma unroll
    for (int g = 0; g < 4; ++g) {
      pm[g] = max3f(sacc[0][g * 4], sacc[0][g * 4 + 1], sacc[0][g * 4 + 2]);
      pm[4 + g] = max3f(sacc[1][g * 4], sacc[1][g * 4 + 1], sacc[1][g * 4 + 2]);
    }
    float pmax = max3f(fmaxf(pm[0], sacc[0][3]), fmaxf(pm[1], sacc[0][7]),
                       fmaxf(pm[2], sacc[0][11]));
    pmax = max3f(pmax, fmaxf(pm[3], sacc[0][15]), fmaxf(pm[4], sacc[1][3]));
    pmax = max3f(pmax, fmaxf(pm[5], sacc[1][7]), fmaxf(pm[6], sacc[1][11]));
    pmax = max3f(pmax, pm[7], sacc[1][15]);
    pmax = fmaxf(pmax, __shfl_xor(pmax, 32, 64));

    if (__any(pmax > mrow + 11.0f)) {  // T13 defer-max (log2 domain)
      const float mnew = fmaxf(mrow, pmax);
      const float sc = __builtin_amdgcn_exp2f(mrow - mnew);
      mrow = mnew;
      lsum *= sc;
#pragma unroll
      for (int reg = 0; reg < 16; ++reg) {
        const float scT = __shfl(sc, (reg & 3) + 8 * (reg >> 2) + 4 * hi, 64);
        accd[0][reg] *= scT;
        accd[1][reg] *= scT;
      }
    }

#pragma unroll
    for (int kf2 = 0; kf2 < 2; ++kf2)
#pragma unroll
      for (int r = 0; r < 16; ++r)
        sacc[kf2][r] = __builtin_amdgcn_exp2f(sacc[kf2][r] - mrow);
    float ps[8];
#pragma unroll
    for (int g = 0; g < 8; ++g) {
      const int kf2 = g >> 2, r0 = (g & 3) * 4;
      ps[g] = (sacc[kf2][r0] + sacc[kf2][r0 + 1]) + (sacc[kf2][r0 + 2] + sacc[kf2][r0 + 3]);
    }
    float psum = ((ps[0] + ps[1]) + (ps[2] + ps[3])) + ((ps[4] + ps[5]) + (ps[6] + ps[7]));
    psum += __shfl_xor(psum, 32, 64);
    lsum += psum;

    // pack P to bf16 dwords: Dd[kf2][rr][dwi] = keys kf2*32 + 8rr + 4hi + 2dwi + {0,1}
    uint32_t Dd[2][4][2];
#pragma unroll
    for (int kf2 = 0; kf2 < 2; ++kf2)
#pragma unroll
      for (int rr = 0; rr < 4; ++rr)
#pragma unroll
        for (int dwi = 0; dwi < 2; ++dwi) {
          uint32_t d;
          float lo = sacc[kf2][rr * 4 + 2 * dwi];
          float hv = sacc[kf2][rr * 4 + 2 * dwi + 1];
          asm("v_cvt_pk_bf16_f32 %0, %1, %2" : "=v"(d) : "v"(lo), "v"(hv));
          Dd[kf2][rr][dwi] = d;
        }

    // redistribute to PV A-fragments via permlane32_swap (T12):
    // swap(Dd[kf2][rA][m], Dd[kf2][rA+1][m]) -> (pa.d[m], pa.d[m+2])
#pragma unroll
    for (int ks = 0; ks < 4; ++ks) {
      const int kf2 = ks >> 1, rA = 2 * (ks & 1);
      uint32_t a0 = Dd[kf2][rA][0], b0 = Dd[kf2][rA + 1][0];
      uint32_t a1 = Dd[kf2][rA][1], b1 = Dd[kf2][rA + 1][1];
      asm("v_permlane32_swap_b32 %0, %1" : "+v"(a0), "+v"(b0));
      asm("v_permlane32_swap_b32 %0, %1" : "+v"(a1), "+v"(b1));
      union { uint32_t d[4]; bf16x8 v; } pa;
      pa.d[0] = a0; pa.d[1] = a1; pa.d[2] = b0; pa.d[3] = b1;
#pragma unroll
      for (int df = 0; df < 2; ++df)
        accd[df] = __builtin_amdgcn_mfma_f32_32x32x16_bf16(pa.v, vfr[df][ks], accd[df], 0, 0, 0);
    }
    __builtin_amdgcn_s_barrier();
  }

#pragma unroll
  for (int reg = 0; reg < 16; ++reg) {
    const int rowq = (reg & 3) + 8 * (reg >> 2) + 4 * hi;
    const float li = 1.0f / __shfl(lsum, rowq, 64);
    u16* orow = O + qkb + (size_t)(qw + rowq) * EMB;
    orow[ql] = f2bf(accd[0][reg] * li);
    orow[32 + ql] = f2bf(accd[1][reg] * li);
  }
}

extern "C" void kernel_launch(void* const* d_in, const int* in_sizes, int n_in,
                              void* d_out, int out_size, void* d_ws, size_t ws_size,
                              hipStream_t stream) {
  const float* x  = (const float*)d_in[0];
  const float* wq = (const float*)d_in[1];
  const float* wk = (const float*)d_in[2];
  const float* wv = (const float*)d_in[3];
  const float* wo = (const float*)d_in[4];

  char* ws = (char*)d_ws;
  u16* xb  = (u16*)(ws + 0);          // 16 MB
  u16* wqb = (u16*)(ws + 16777216);   //  2 MB each
  u16* wkb = (u16*)(ws + 18874368);
  u16* wvb = (u16*)(ws + 20971520);
  u16* wob = (u16*)(ws + 23068672);
  u16* Qb  = (u16*)(ws + 25165824);   // 16 MB, [B,S,E], pre-scaled 0.125*log2e
  u16* Kb  = (u16*)(ws + 41943040);   // 16 MB, [B,S,E]
  u16* VTb = (u16*)(ws + 58720256);   // 16 MB, [B,H,D,S]
  u16* AO  = (u16*)(ws + 75497472);   // 16 MB, [B,S,E]

  cvt_f32_bf16<<<2097152 / 256, 256, 0, stream>>>(x, xb, 2097152);
  cvt_f32_bf16<<<262144 / 256, 256, 0, stream>>>(wq, wqb, 262144);
  cvt_f32_bf16<<<262144 / 256, 256, 0, stream>>>(wk, wkb, 262144);
  cvt_f32_bf16<<<262144 / 256, 256, 0, stream>>>(wv, wvb, 262144);
  cvt_f32_bf16<<<262144 / 256, 256, 0, stream>>>(wo, wob, 262144);

  gemm_qkv<<<dim3(8, 64, 3), 256, 0, stream>>>(xb, wqb, wkb, wvb, Qb, Kb, VTb);
  attn_fwd<<<dim3(16, 64), 256, 0, stream>>>(Qb, Kb, VTb, AO);
  gemm_out<<<dim3(8, 64), 256, 0, stream>>>(AO, wob, (float*)d_out);
}